// Round 7
// baseline (4385.746 us; speedup 1.0000x reference)
//
#include <hip/hip_runtime.h>
#include <cmath>

#define HID 150
#define FOURH 600
#define BATCH 64
#define TLEN 2048
#define NKS 5  // 32-wide k-slices over k padded 150->160

typedef __attribute__((ext_vector_type(2))) _Float16 half2_t;

#if defined(__has_builtin)
#if __has_builtin(__builtin_amdgcn_fdot2)
#define FDOT2(a, b, c) __builtin_amdgcn_fdot2((a), (b), (c), false)
#endif
#endif
#ifndef FDOT2
__device__ __forceinline__ float fdot2_fb(half2_t a, half2_t b, float c) {
    return c + (float)a.x * (float)b.x + (float)a.y * (float)b.y;
}
#define FDOT2(a, b, c) fdot2_fb((a), (b), (c))
#endif

__device__ __forceinline__ float sigmoidf_(float x) {
    return 1.0f / (1.0f + __expf(-x));
}
__device__ __forceinline__ float tanhf_(float x) {
    return 1.0f - 2.0f / (__expf(2.0f * x) + 1.0f);
}

// x_proj[b, i, c] = bias[c] + sum_k X[b, t0+i, k] * Wx[k, c]   (f32)
__global__ __launch_bounds__(640, 2) void xproj_gemm(
    const float* __restrict__ X,     // [BATCH, TLEN, 150]
    const float* __restrict__ Wx,    // [150, 600]
    const float* __restrict__ bias,  // [600]
    float* __restrict__ xp,          // [BATCH, C, 600]
    int t0, int C)
{
    const int blocks_per_batch = C / 32;
    const int b  = blockIdx.x / blocks_per_batch;
    const int i0 = (blockIdx.x % blocks_per_batch) * 32;
    const float* Xbase = X + ((size_t)(b * TLEN + t0 + i0)) * HID;

    __shared__ __align__(16) float xt[150 * 36];
    const int tid = threadIdx.x;
    for (int i = tid; i < 32 * HID; i += 640) {
        int r = i / HID, k = i % HID;
        xt[k * 36 + r] = Xbase[(size_t)r * HID + k];
    }
    __syncthreads();

    if (tid < FOURH) {
        float acc[32];
        #pragma unroll
        for (int r = 0; r < 32; ++r) acc[r] = 0.f;
        for (int k = 0; k < HID; ++k) {
            float w = Wx[(size_t)k * FOURH + tid];
            #pragma unroll
            for (int r4 = 0; r4 < 8; ++r4) {
                float4 xv = *(const float4*)&xt[k * 36 + r4 * 4];
                acc[r4*4+0] += xv.x * w;
                acc[r4*4+1] += xv.y * w;
                acc[r4*4+2] += xv.z * w;
                acc[r4*4+3] += xv.w * w;
            }
        }
        float bv = bias[tid];
        float* o = xp + ((size_t)b * C + i0) * FOURH + tid;
        #pragma unroll
        for (int r = 0; r < 32; ++r) o[(size_t)r * FOURH] = acc[r] + bv;
    }
}

// Pack Wh (f32 [150,600]) into per-thread-sliced half2 layout:
// whp[layer][ks*9600 + (g*16+p)*150 + j] = (Wh[32ks+2p][g*150+j], Wh[32ks+2p+1][...])
__global__ void pack_wh(const float* __restrict__ Wh0, const float* __restrict__ Wh1,
                        half2_t* __restrict__ whp) {
    int idx = blockIdx.x * 256 + threadIdx.x;
    if (idx >= 2 * 48000) return;
    int layer = idx / 48000, r = idx - layer * 48000;
    int j = r % HID, t = r / HID;       // t = (ks*4+g)*16+p
    int p = t & 15, gks = t >> 4;
    int g = gks & 3, ks = gks >> 2;
    const float* Wh = layer ? Wh1 : Wh0;
    int k0 = ks * 32 + 2 * p;
    float a  = (k0 < HID)     ? Wh[(size_t)k0 * FOURH + g * HID + j]       : 0.f;
    float bb = (k0 + 1 < HID) ? Wh[(size_t)(k0 + 1) * FOURH + g * HID + j] : 0.f;
    half2_t h; h.x = (_Float16)a; h.y = (_Float16)bb;
    whp[idx] = h;
}

// ---- literal-index weight machinery ----
#define WL(arr, G, P) arr[(P)] = Wj[((G) * 16 + (P)) * HID];
#define WL16(arr, G) WL(arr,G,0) WL(arr,G,1) WL(arr,G,2) WL(arr,G,3) WL(arr,G,4) \
  WL(arr,G,5) WL(arr,G,6) WL(arr,G,7) WL(arr,G,8) WL(arr,G,9) WL(arr,G,10) \
  WL(arr,G,11) WL(arr,G,12) WL(arr,G,13) WL(arr,G,14) WL(arr,G,15)

// One quarter of the k-slice for TWO batch elements: 2x16B LDS reads of h,
// 32 fdot2 sharing the same 16 weight registers (weight stream amortized 2x
// -- the compiler remats weight loads per step; reuse makes that cheap).
#define DOTQ2(Q) { \
  float4 hu = *(const float4*)(const void*)&h16[0][ks * 32 + (Q) * 8]; \
  float4 hv = *(const float4*)(const void*)&h16[1][ks * 32 + (Q) * 8]; \
  half2_t u0 = __builtin_bit_cast(half2_t, hu.x); \
  half2_t u1 = __builtin_bit_cast(half2_t, hu.y); \
  half2_t u2 = __builtin_bit_cast(half2_t, hu.z); \
  half2_t u3 = __builtin_bit_cast(half2_t, hu.w); \
  half2_t v0 = __builtin_bit_cast(half2_t, hv.x); \
  half2_t v1 = __builtin_bit_cast(half2_t, hv.y); \
  half2_t v2 = __builtin_bit_cast(half2_t, hv.z); \
  half2_t v3 = __builtin_bit_cast(half2_t, hv.w); \
  a00 = FDOT2(u0, w0[(Q)*4+0], a00); a10 = FDOT2(v0, w0[(Q)*4+0], a10); \
  a00 = FDOT2(u1, w0[(Q)*4+1], a00); a10 = FDOT2(v1, w0[(Q)*4+1], a10); \
  a00 = FDOT2(u2, w0[(Q)*4+2], a00); a10 = FDOT2(v2, w0[(Q)*4+2], a10); \
  a00 = FDOT2(u3, w0[(Q)*4+3], a00); a10 = FDOT2(v3, w0[(Q)*4+3], a10); \
  a01 = FDOT2(u0, w1[(Q)*4+0], a01); a11 = FDOT2(v0, w1[(Q)*4+0], a11); \
  a01 = FDOT2(u1, w1[(Q)*4+1], a01); a11 = FDOT2(v1, w1[(Q)*4+1], a11); \
  a01 = FDOT2(u2, w1[(Q)*4+2], a01); a11 = FDOT2(v2, w1[(Q)*4+2], a11); \
  a01 = FDOT2(u3, w1[(Q)*4+3], a01); a11 = FDOT2(v3, w1[(Q)*4+3], a11); \
  a02 = FDOT2(u0, w2[(Q)*4+0], a02); a12 = FDOT2(v0, w2[(Q)*4+0], a12); \
  a02 = FDOT2(u1, w2[(Q)*4+1], a02); a12 = FDOT2(v1, w2[(Q)*4+1], a12); \
  a02 = FDOT2(u2, w2[(Q)*4+2], a02); a12 = FDOT2(v2, w2[(Q)*4+2], a12); \
  a02 = FDOT2(u3, w2[(Q)*4+3], a02); a12 = FDOT2(v3, w2[(Q)*4+3], a12); \
  a03 = FDOT2(u0, w3[(Q)*4+0], a03); a13 = FDOT2(v0, w3[(Q)*4+0], a13); \
  a03 = FDOT2(u1, w3[(Q)*4+1], a03); a13 = FDOT2(v1, w3[(Q)*4+1], a13); \
  a03 = FDOT2(u2, w3[(Q)*4+2], a03); a13 = FDOT2(v2, w3[(Q)*4+2], a13); \
  a03 = FDOT2(u3, w3[(Q)*4+3], a03); a13 = FDOT2(v3, w3[(Q)*4+3], a13); }

// Dual-part recurrence, G=2 batch elements per WG.
// Grid 64 (dual): WGs 0-31 = part A, 32-63 = part B. Grid 32 (single): part A.
// WG bg handles batches {2bg, 2bg+1}. 768 threads; thread (j, ks) streams its
// 64 packed-half2 weight slice from L2 once per step, applies it to BOTH
// batches' h (2x arithmetic intensity on the L2 weight stream).
__global__ __launch_bounds__(768)
__attribute__((amdgpu_waves_per_eu(3, 3)))
void lstm_recur2(const float* __restrict__ xpA, const half2_t* __restrict__ whpA,
                 float* __restrict__ stA, int t0A,
                 const float* __restrict__ xpB, const half2_t* __restrict__ whpB,
                 float* __restrict__ stB, int t0B,
                 float* __restrict__ out, int C)
{
    const int part = blockIdx.x >> 5;
    const int b0 = (blockIdx.x & 31) * 2;
    const int tid = threadIdx.x;
    const int tidc = (tid < 750) ? tid : 749;   // clamp: unconditional indexing
    const int ks = tidc / HID;       // 0..4
    const int j  = tidc - ks * HID;  // 0..149

    const float*   xp    = part ? xpB  : xpA;
    const half2_t* whp   = part ? whpB : whpA;
    float*         state = part ? stB  : stA;
    const int      t0    = part ? t0B  : t0A;

    __shared__ __align__(16) _Float16 h16[2][160];          // h as f16, tails zero
    __shared__ __align__(16) float part_s[2][NKS][4][152];  // [bb][ks][g][j]

    half2_t w0[16], w1[16], w2[16], w3[16];
    {
        const half2_t* Wj = whp + (size_t)ks * 9600 + j;
        WL16(w0, 0) WL16(w1, 1) WL16(w2, 2) WL16(w3, 3)
    }

    // Stage-B thread mapping: tid < 300 -> (bb, jj)
    const int tidb = (tid < 300) ? tid : 299;
    const int bb = tidb / HID;       // 0..1
    const int jj = tidb - bb * HID;  // 0..149

    // init h (f16, flat 320) and c
    if (tid < 320) {
        int hb = tid / 160, hj = tid - hb * 160;
        float hv = 0.f;
        if (t0 != 0 && hj < HID) hv = state[(b0 + hb) * 300 + HID + hj];
        h16[hb][hj] = (_Float16)hv;
    }
    float cst = 0.f;
    if (t0 != 0 && tid < 300) cst = state[(b0 + bb) * 300 + jj];
    __syncthreads();

    const float* xpb = xp + (size_t)(b0 + bb) * C * FOURH;
    float* outb = out + ((size_t)(b0 + bb) * TLEN + t0) * HID;

    float xn0 = 0.f, xn1 = 0.f, xn2 = 0.f, xn3 = 0.f;
    if (tid < 300) {
        xn0 = xpb[jj];
        xn1 = xpb[HID + jj];
        xn2 = xpb[2 * HID + jj];
        xn3 = xpb[3 * HID + jj];
    }

    for (int i = 0; i < C; ++i) {
        // ---- Stage A: 128 v_dot2 per thread, 2 batches (750 threads) ----
        if (tid < 750) {
            float a00 = 0.f, a01 = 0.f, a02 = 0.f, a03 = 0.f;
            float a10 = 0.f, a11 = 0.f, a12 = 0.f, a13 = 0.f;
            DOTQ2(0) DOTQ2(1) DOTQ2(2) DOTQ2(3)
            part_s[0][ks][0][j] = a00;
            part_s[0][ks][1][j] = a01;
            part_s[0][ks][2][j] = a02;
            part_s[0][ks][3][j] = a03;
            part_s[1][ks][0][j] = a10;
            part_s[1][ks][1][j] = a11;
            part_s[1][ks][2][j] = a12;
            part_s[1][ks][3][j] = a13;
        }
        __syncthreads();

        // ---- Stage B: reduce, activate, update c/h (300 threads) ----
        if (tid < 300) {
            float p0 = xn0, p1 = xn1, p2 = xn2, p3 = xn3;
            if (i + 1 < C) {
                const float* p = &xpb[(size_t)(i + 1) * FOURH];
                xn0 = p[jj];
                xn1 = p[HID + jj];
                xn2 = p[2 * HID + jj];
                xn3 = p[3 * HID + jj];
            }
            float z0 = p0, z1 = p1, z2 = p2, z3 = p3;
            #pragma unroll
            for (int s = 0; s < NKS; ++s) {
                z0 += part_s[bb][s][0][jj];
                z1 += part_s[bb][s][1][jj];
                z2 += part_s[bb][s][2][jj];
                z3 += part_s[bb][s][3][jj];
            }
            float ig = sigmoidf_(z0);
            float fg = sigmoidf_(z1);
            float gg = tanhf_(z2);
            float og = sigmoidf_(z3);
            cst = fg * cst + ig * gg;
            float hn = og * tanhf_(cst);
            h16[bb][jj] = (_Float16)hn;
            outb[(size_t)i * HID + jj] = hn;
        }
        __syncthreads();
    }

    if (tid < 300) {
        state[(b0 + bb) * 300 + jj] = cst;
        state[(b0 + bb) * 300 + HID + jj] = (float)h16[bb][jj];
    }
}

extern "C" void kernel_launch(void* const* d_in, const int* in_sizes, int n_in,
                              void* d_out, int out_size, void* d_ws, size_t ws_size,
                              hipStream_t stream) {
    const float* xs  = (const float*)d_in[0];
    const float* Wx0 = (const float*)d_in[1];
    const float* Wh0 = (const float*)d_in[2];
    const float* b0  = (const float*)d_in[3];
    const float* Wx1 = (const float*)d_in[4];
    const float* Wh1 = (const float*)d_in[5];
    const float* b1  = (const float*)d_in[6];
    float* out = (float*)d_out;

    // Chunk size: two xp buffers + packed weights + states must fit in ws.
    int C = 256;
    while (C > 32) {
        size_t need = 2 * (size_t)BATCH * C * FOURH * 4    // xp0, xp1
                    + 2 * 48000 * 4                        // whp (half2 = 4B)
                    + 2 * (size_t)BATCH * 300 * 4;         // states
        if (need <= ws_size) break;
        C >>= 1;
    }
    char* w = (char*)d_ws;
    float* xp0 = (float*)w;                 w += (size_t)BATCH * C * FOURH * 4;
    float* xp1 = (float*)w;                 w += (size_t)BATCH * C * FOURH * 4;
    half2_t* whp0 = (half2_t*)w;            w += 48000 * 4;
    half2_t* whp1 = (half2_t*)w;            w += 48000 * 4;
    float* st0 = (float*)w;                 w += (size_t)BATCH * 300 * 4;
    float* st1 = (float*)w;

    pack_wh<<<dim3((2 * 48000 + 255) / 256), dim3(256), 0, stream>>>(Wh0, Wh1, whp0);

    const int nchunk = TLEN / C;
    const int gpb = C / 32;  // xproj blocks per batch

    // Software pipeline: slot s runs L0 chunk s and L1 chunk s-1 concurrently.
    for (int s = 0; s <= nchunk; ++s) {
        const bool hasA = (s < nchunk);   // L0 chunk s
        const bool hasB = (s >= 1);       // L1 chunk s-1
        if (hasA)
            xproj_gemm<<<dim3(BATCH * gpb), dim3(640), 0, stream>>>(
                xs, Wx0, b0, xp0, s * C, C);
        if (hasB)
            xproj_gemm<<<dim3(BATCH * gpb), dim3(640), 0, stream>>>(
                out, Wx1, b1, xp1, (s - 1) * C, C);
        if (hasA && hasB)
            lstm_recur2<<<dim3(64), dim3(768), 0, stream>>>(
                xp0, whp0, st0, s * C, xp1, whp1, st1, (s - 1) * C, out, C);
        else if (hasA)
            lstm_recur2<<<dim3(32), dim3(768), 0, stream>>>(
                xp0, whp0, st0, s * C, nullptr, nullptr, nullptr, 0, out, C);
        else
            lstm_recur2<<<dim3(32), dim3(768), 0, stream>>>(
                xp1, whp1, st1, (s - 1) * C, nullptr, nullptr, nullptr, 0, out, C);
    }
}